// Round 5
// baseline (302.237 us; speedup 1.0000x reference)
//
#include <hip/hip_runtime.h>
#include <stdint.h>

// Problem constants
#define BATCH 512
#define HWIMG 78400      // 280*280
#define WROW  280
#define KSZ   28
#define PNUM  100        // 10x10 patches
#define FNUM  16
#define ONUM  10

#define BT    64         // batches per block
#define NCH   14         // chunks of 2 kernel-rows
#define XSTR  15         // padded f4 stride per batch (14 data + 1 pad; breaks 4-way bank conflict)
#define XF4   1024       // x buffer f4 count (64*15=960, padded to 1024 for uniform DMA sweeps)
#define WF4   256        // w buffer f4 count (16*14=224, padded to 256)

typedef __attribute__((address_space(1))) const void cg_void;
typedef __attribute__((address_space(3))) void lds_void;

__global__ __launch_bounds__(256) void init_out(const float* __restrict__ dec_b,
                                                float* __restrict__ out) {
    int i = blockIdx.x * 256 + threadIdx.x;
    if (i < BATCH * ONUM) out[i] = dec_b[i % ONUM];
}

// Block: one patch p, 64 batches, 16 filters. 256 threads = kg(8) x fg(2) x bg(16).
// Per-thread tile 4 batches x 8 filters. LDS = 40960 B -> exactly 4 blocks/CU,
// all 800 blocks co-resident (no dispatch tail). 2-row chunks, double-buffered
// global_load_lds DMA with uniform 5 instr/chunk/wave -> manual vmcnt(5).
__global__ __launch_bounds__(256, 4) void lcn_fused(
    const float* __restrict__ x,      // (512,1,280,280)
    const float* __restrict__ weight, // (1600,1,28,28)  index (f*100+p)*784
    const float* __restrict__ bias,   // (1600,1)        index  f*100+p
    const float* __restrict__ dec_w,  // (10,1600)       index  o*1600+f*100+p
    float* __restrict__ out)          // (512,10) pre-initialized with dec_b
{
    __shared__ float4 lx[2][XF4];   // [buf][b*15 + r*7 + c4]   (r in 0..1 within chunk)
    __shared__ float4 lw[2][WF4];   // [buf][f*14 + r*7 + c4]

    const int t  = threadIdx.x;
    const int kg = t & 7;           // k-slice (lane bits 0..2): f4 column within row
    const int fg = (t >> 3) & 1;    // filter group (lane bit 3): 8 filters each
    const int bg = t >> 4;          // batch group 0..15: 4 batches each
    const int bx = blockIdx.x;
    const int p  = bx >> 3;         // 0..99
    const int bt = bx & 7;
    const int pr = p / 10, pc = p % 10;
    const int b0 = bt * BT;

    // ---- DMA source pointers (prologue; per-chunk just adds a row offset).
    // x: 4 sweeps of 256 f4; slot = s*256+t -> b=slot/15, rf=slot%15 (rf==14 & slot>=960 are pads).
    const float* xsrc[4];
#pragma unroll
    for (int s = 0; s < 4; ++s) {
        int slot = s * 256 + t;
        int b = slot / XSTR, rf = slot % XSTR;
        if (slot >= 960 || rf >= 14) { b = 0; rf = 0; }   // clamp pad lanes (harmless dup load)
        int r = rf / 7, c4 = rf % 7;
        xsrc[s] = x + (size_t)(b0 + b) * HWIMG + (size_t)(pr * 28 + r) * WROW + pc * 28 + c4 * 4;
    }
    // w: 1 sweep of 256 f4; slots 224..255 clamped.
    const float* wsrc;
    {
        int slot = (t < 224) ? t : 0;
        int f = slot / 14, rf = slot % 14;
        int r = rf / 7, c4 = rf % 7;
        wsrc = weight + (size_t)(f * PNUM + p) * 784 + r * KSZ + c4 * 4;
    }

    auto issue_chunk = [&](int cc, int bb) {
#pragma unroll
        for (int s = 0; s < 4; ++s)
            __builtin_amdgcn_global_load_lds((cg_void*)(xsrc[s] + (size_t)cc * 2 * WROW),
                                             (lds_void*)&lx[bb][s * 256 + t], 16, 0, 0);
        __builtin_amdgcn_global_load_lds((cg_void*)(wsrc + (size_t)cc * 2 * KSZ),
                                         (lds_void*)&lw[bb][t], 16, 0, 0);
    };

    issue_chunk(0, 0);
    issue_chunk(1, 1);

    float acc[4][8];
#pragma unroll
    for (int i = 0; i < 4; ++i)
#pragma unroll
        for (int j = 0; j < 8; ++j) acc[i][j] = 0.f;

    const int kge = (kg < 7) ? kg : 0;   // kg==7 duplicates kg==0, masked later

#pragma unroll
    for (int c = 0; c < NCH; ++c) {
        const int buf = c & 1;
        // chunk c's 5 DMAs done; chunk c+1's 5 stay in flight.
        if (c < NCH - 1) asm volatile("s_waitcnt vmcnt(5)" ::: "memory");
        else             asm volatile("s_waitcnt vmcnt(0)" ::: "memory");
        __builtin_amdgcn_s_barrier();
        asm volatile("" ::: "memory");

#pragma unroll
        for (int r = 0; r < 2; ++r) {
            float4 wv[8];
#pragma unroll
            for (int j = 0; j < 8; ++j)
                wv[j] = lw[buf][(fg * 8 + j) * 14 + r * 7 + kge];
#pragma unroll
            for (int i = 0; i < 4; ++i) {
                float4 av = lx[buf][(bg * 4 + i) * XSTR + r * 7 + kge];
#pragma unroll
                for (int j = 0; j < 8; ++j) {
                    acc[i][j] = fmaf(av.x, wv[j].x, acc[i][j]);
                    acc[i][j] = fmaf(av.y, wv[j].y, acc[i][j]);
                    acc[i][j] = fmaf(av.z, wv[j].z, acc[i][j]);
                    acc[i][j] = fmaf(av.w, wv[j].w, acc[i][j]);
                }
            }
        }

        asm volatile("s_waitcnt lgkmcnt(0)" ::: "memory");
        __builtin_amdgcn_s_barrier();        // all waves done reading buf
        asm volatile("" ::: "memory");
        if (c + 2 < NCH) issue_chunk(c + 2, buf);
    }

    // kg==7 computed duplicated data: zero it.
    const float km = (kg < 7) ? 1.f : 0.f;
#pragma unroll
    for (int i = 0; i < 4; ++i)
#pragma unroll
        for (int j = 0; j < 8; ++j) acc[i][j] *= km;

    // Reduce over kg (lane bits 0..2) — butterfly; all lanes end with the full dot.
#pragma unroll
    for (int d = 1; d < 8; d <<= 1)
#pragma unroll
        for (int i = 0; i < 4; ++i)
#pragma unroll
            for (int j = 0; j < 8; ++j)
                acc[i][j] += __shfl_xor(acc[i][j], d, 64);

    // bias + relu
    float y[4][8];
#pragma unroll
    for (int j = 0; j < 8; ++j) {
        const float bs = bias[(fg * 8 + j) * PNUM + p];
#pragma unroll
        for (int i = 0; i < 4; ++i) {
            float v = acc[i][j] + bs;
            y[i][j] = v > 0.f ? v : 0.f;
        }
    }

    // Decoder: split the 10 outputs across kg lanes 0..4 (2 outputs each).
    float po[4][2];
    const int  o0  = kg * 2;
    const bool act = (kg < 5);
    if (act) {
        float dwv[8][2];
#pragma unroll
        for (int j = 0; j < 8; ++j)
#pragma unroll
            for (int oo = 0; oo < 2; ++oo)
                dwv[j][oo] = dec_w[(size_t)(o0 + oo) * (PNUM * FNUM) + (fg * 8 + j) * PNUM + p];
#pragma unroll
        for (int i = 0; i < 4; ++i)
#pragma unroll
            for (int oo = 0; oo < 2; ++oo) {
                float s = 0.f;
#pragma unroll
                for (int j = 0; j < 8; ++j) s = fmaf(y[i][j], dwv[j][oo], s);
                po[i][oo] = s;
            }
    } else {
#pragma unroll
        for (int i = 0; i < 4; ++i) { po[i][0] = 0.f; po[i][1] = 0.f; }
    }

    // Reduce over fg (lane bit 3); kg bits preserved so zero lanes stay isolated.
#pragma unroll
    for (int i = 0; i < 4; ++i)
#pragma unroll
        for (int oo = 0; oo < 2; ++oo)
            po[i][oo] += __shfl_xor(po[i][oo], 8, 64);

    if (act && fg == 0) {
#pragma unroll
        for (int i = 0; i < 4; ++i)
#pragma unroll
            for (int oo = 0; oo < 2; ++oo)
                atomicAdd(&out[(size_t)(b0 + bg * 4 + i) * ONUM + o0 + oo], po[i][oo]);
    }
}

extern "C" void kernel_launch(void* const* d_in, const int* in_sizes, int n_in,
                              void* d_out, int out_size, void* d_ws, size_t ws_size,
                              hipStream_t stream) {
    const float* x     = (const float*)d_in[0];
    const float* w     = (const float*)d_in[1];
    const float* bias  = (const float*)d_in[2];
    const float* dec_w = (const float*)d_in[3];
    const float* dec_b = (const float*)d_in[4];
    float* out = (float*)d_out;

    init_out<<<(BATCH * ONUM + 255) / 256, 256, 0, stream>>>(dec_b, out);
    lcn_fused<<<(BATCH / BT) * PNUM, 256, 0, stream>>>(x, w, bias, dec_w, out);
}

// Round 6
// 275.277 us; speedup vs baseline: 1.0979x; 1.0979x over previous
//
#include <hip/hip_runtime.h>
#include <stdint.h>

// Problem constants
#define BATCH 512
#define HWIMG 78400      // 280*280
#define WROW  280
#define KSZ   28
#define PNUM  100        // 10x10 patches
#define FNUM  16
#define ONUM  10

#define BT    64         // batches per block
#define NCH   14         // chunks of 2 kernel-rows
#define XSTR  15         // f4 stride per batch in lx (14 data + 1 pad)
#define WSTR  15         // f4 stride per filter in lw (14 data + 1 pad; odd -> no 4-way fg conflict)
#define XF4   1024       // lx slots per buffer (64*15=960 -> 4 uniform sweeps of 256)
#define WF4   256        // lw slots per buffer (16*15=240 -> 1 sweep of 256)

typedef __attribute__((address_space(1))) const void cg_void;
typedef __attribute__((address_space(3))) void lds_void;

__global__ __launch_bounds__(256) void init_out(const float* __restrict__ dec_b,
                                                float* __restrict__ out) {
    int i = blockIdx.x * 256 + threadIdx.x;
    if (i < BATCH * ONUM) out[i] = dec_b[i % ONUM];
}

// Block: one patch p, 64 batches, 16 filters. 256 threads = kg(8) x fg(4) x bg(8).
// Per-thread tile 8 batches x 4 filters (R3's register-lean mapping: wv[4] not wv[8]).
// LDS = 2*(1024+256)*16 = 40960 B -> 4 blocks/CU; 800 blocks all co-resident.
// Bank-conflict-free: bg stride = 8*XSTR f4 (== 0 mod 8, collapses), fg stride
// = 4*WSTR f4 (odd WSTR -> mod 8 = 4, splits). All reads <=2-way (free, m136).
// NO launch_bounds waves hint: R4's cap made the compiler spill (114 MB writes).
__global__ __launch_bounds__(256) void lcn_fused(
    const float* __restrict__ x,      // (512,1,280,280)
    const float* __restrict__ weight, // (1600,1,28,28)  index (f*100+p)*784
    const float* __restrict__ bias,   // (1600,1)        index  f*100+p
    const float* __restrict__ dec_w,  // (10,1600)       index  o*1600+f*100+p
    float* __restrict__ out)          // (512,10) pre-initialized with dec_b
{
    __shared__ float4 lx[2][XF4];   // [buf][b*15 + r*7 + c4], r in 0..1
    __shared__ float4 lw[2][WF4];   // [buf][f*15 + r*7 + c4]

    const int t  = threadIdx.x;
    const int kg = t & 7;           // k-slice (lane bits 0..2): f4 column within row
    const int fg = (t >> 3) & 3;    // filter group (lane bits 3..4): 4 filters each
    const int bg = t >> 5;          // batch group 0..7: 8 batches each
    const int bx = blockIdx.x;
    const int p  = bx >> 3;         // 0..99
    const int bt = bx & 7;
    const int pr = p / 10, pc = p % 10;
    const int b0 = bt * BT;

    // ---- DMA source pointers (prologue; per-chunk adds a row offset).
    // lx: 4 sweeps of 256 f4. slot = s*256+t -> b = slot/15, rf = slot%15.
    // rf==14 or b>=64 are pad slots: clamp to (0,0) (harmless dup, never read).
    const float* xsrc[4];
#pragma unroll
    for (int s = 0; s < 4; ++s) {
        int slot = s * 256 + t;
        int b = slot / XSTR, rf = slot % XSTR;
        if (b >= BT || rf >= 14) { b = 0; rf = 0; }
        int r = rf / 7, c4 = rf % 7;
        xsrc[s] = x + (size_t)(b0 + b) * HWIMG + (size_t)(pr * 28 + r) * WROW + pc * 28 + c4 * 4;
    }
    // lw: 1 sweep of 256 f4. slot = t -> f = t/15, rf = t%15; pads clamped.
    const float* wsrc;
    {
        int f = t / WSTR, rf = t % WSTR;
        if (f >= FNUM || rf >= 14) { f = 0; rf = 0; }
        int r = rf / 7, c4 = rf % 7;
        wsrc = weight + (size_t)(f * PNUM + p) * 784 + r * KSZ + c4 * 4;
    }

    auto issue_chunk = [&](int cc, int bb) {
#pragma unroll
        for (int s = 0; s < 4; ++s)
            __builtin_amdgcn_global_load_lds((cg_void*)(xsrc[s] + (size_t)cc * 2 * WROW),
                                             (lds_void*)&lx[bb][s * 256 + t], 16, 0, 0);
        __builtin_amdgcn_global_load_lds((cg_void*)(wsrc + (size_t)cc * 2 * KSZ),
                                         (lds_void*)&lw[bb][t], 16, 0, 0);
    };

    issue_chunk(0, 0);
    issue_chunk(1, 1);

    float acc[8][4];
#pragma unroll
    for (int i = 0; i < 8; ++i)
#pragma unroll
        for (int j = 0; j < 4; ++j) acc[i][j] = 0.f;

    const int kge = (kg < 7) ? kg : 0;   // kg==7 duplicates kg==0, masked later

#pragma unroll 2
    for (int c = 0; c < NCH; ++c) {
        const int buf = c & 1;
        // chunk c's 5 DMAs landed; chunk c+1's 5 stay in flight across the barrier.
        if (c + 1 < NCH) asm volatile("s_waitcnt vmcnt(5)" ::: "memory");
        else             asm volatile("s_waitcnt vmcnt(0)" ::: "memory");
        __builtin_amdgcn_s_barrier();
        asm volatile("" ::: "memory");

#pragma unroll
        for (int r = 0; r < 2; ++r) {
            float4 wv[4];
#pragma unroll
            for (int j = 0; j < 4; ++j)
                wv[j] = lw[buf][(fg * 4 + j) * WSTR + r * 7 + kge];
#pragma unroll
            for (int i = 0; i < 8; ++i) {
                float4 av = lx[buf][(bg * 8 + i) * XSTR + r * 7 + kge];
#pragma unroll
                for (int j = 0; j < 4; ++j) {
                    acc[i][j] = fmaf(av.x, wv[j].x, acc[i][j]);
                    acc[i][j] = fmaf(av.y, wv[j].y, acc[i][j]);
                    acc[i][j] = fmaf(av.z, wv[j].z, acc[i][j]);
                    acc[i][j] = fmaf(av.w, wv[j].w, acc[i][j]);
                }
            }
        }

        asm volatile("" ::: "memory");
        __builtin_amdgcn_s_barrier();        // all waves done reading buf
        asm volatile("" ::: "memory");
        if (c + 2 < NCH) issue_chunk(c + 2, buf);
    }

    // kg==7 computed duplicated data: zero it.
    const float km = (kg < 7) ? 1.f : 0.f;
#pragma unroll
    for (int i = 0; i < 8; ++i)
#pragma unroll
        for (int j = 0; j < 4; ++j) acc[i][j] *= km;

    // Reduce over kg (lane bits 0..2) — butterfly; all lanes end with the full dot.
#pragma unroll
    for (int d = 1; d < 8; d <<= 1)
#pragma unroll
        for (int i = 0; i < 8; ++i)
#pragma unroll
            for (int j = 0; j < 4; ++j)
                acc[i][j] += __shfl_xor(acc[i][j], d, 64);

    // bias + relu
    float y[8][4];
#pragma unroll
    for (int j = 0; j < 4; ++j) {
        const float bs = bias[(fg * 4 + j) * PNUM + p];
#pragma unroll
        for (int i = 0; i < 8; ++i) {
            float v = acc[i][j] + bs;
            y[i][j] = v > 0.f ? v : 0.f;
        }
    }

    // Decoder: split the 10 outputs across kg lanes 0..4 (2 outputs each).
    float po[8][2];
    const int  o0  = kg * 2;
    const bool act = (kg < 5);
    if (act) {
        float dwv[4][2];
#pragma unroll
        for (int j = 0; j < 4; ++j)
#pragma unroll
            for (int oo = 0; oo < 2; ++oo)
                dwv[j][oo] = dec_w[(size_t)(o0 + oo) * (PNUM * FNUM) + (fg * 4 + j) * PNUM + p];
#pragma unroll
        for (int i = 0; i < 8; ++i)
#pragma unroll
            for (int oo = 0; oo < 2; ++oo) {
                float s = 0.f;
#pragma unroll
                for (int j = 0; j < 4; ++j) s = fmaf(y[i][j], dwv[j][oo], s);
                po[i][oo] = s;
            }
    } else {
#pragma unroll
        for (int i = 0; i < 8; ++i) { po[i][0] = 0.f; po[i][1] = 0.f; }
    }

    // Reduce over fg (lane bits 3..4); kg bits preserved so zero lanes stay isolated.
#pragma unroll
    for (int d = 8; d < 32; d <<= 1)
#pragma unroll
        for (int i = 0; i < 8; ++i)
#pragma unroll
            for (int oo = 0; oo < 2; ++oo)
                po[i][oo] += __shfl_xor(po[i][oo], d, 64);

    if (act && fg == 0) {
#pragma unroll
        for (int i = 0; i < 8; ++i)
#pragma unroll
            for (int oo = 0; oo < 2; ++oo)
                atomicAdd(&out[(size_t)(b0 + bg * 8 + i) * ONUM + o0 + oo], po[i][oo]);
    }
}

extern "C" void kernel_launch(void* const* d_in, const int* in_sizes, int n_in,
                              void* d_out, int out_size, void* d_ws, size_t ws_size,
                              hipStream_t stream) {
    const float* x     = (const float*)d_in[0];
    const float* w     = (const float*)d_in[1];
    const float* bias  = (const float*)d_in[2];
    const float* dec_w = (const float*)d_in[3];
    const float* dec_b = (const float*)d_in[4];
    float* out = (float*)d_out;

    init_out<<<(BATCH * ONUM + 255) / 256, 256, 0, stream>>>(dec_b, out);
    lcn_fused<<<(BATCH / BT) * PNUM, 256, 0, stream>>>(x, w, bias, dec_w, out);
}

// Round 7
// 265.648 us; speedup vs baseline: 1.1377x; 1.0362x over previous
//
#include <hip/hip_runtime.h>

// Problem constants
#define BATCH 512
#define HWIMG 78400      // 280*280
#define WROW  280
#define KSZ   28
#define PNUM  100        // 10x10 patches
#define FNUM  16
#define ONUM  10

__global__ __launch_bounds__(256) void init_out(const float* __restrict__ dec_b,
                                                float* __restrict__ out) {
    int i = blockIdx.x * 256 + threadIdx.x;
    if (i < BATCH * ONUM) out[i] = dec_b[i % ONUM];
}

// Streaming design: NO LDS, NO barriers, NO double-buffer arrays.
// Block: one patch p, 64 batches, 16 filters. 256 threads = kg(8) x fg(4) x bg(8).
// Per-thread tile 8 batches x 4 filters: 12 independent float4 loads feed 128 FMA
// per k-row; loads batch up (MLP) and free-running waves (no barrier convoy)
// keep the HBM request stream smooth. w is L2-hot (8 consecutive blocks share p).
// No launch_bounds waves cap: the allocator takes ~100-130 VGPR without spilling
// (R5 evidence); a cap caused the R2/R4 scratch spills.
__global__ __launch_bounds__(256) void lcn_fused(
    const float* __restrict__ x,      // (512,1,280,280)
    const float* __restrict__ weight, // (1600,1,28,28)  index (f*100+p)*784
    const float* __restrict__ bias,   // (1600,1)        index  f*100+p
    const float* __restrict__ dec_w,  // (10,1600)       index  o*1600+f*100+p
    float* __restrict__ out)          // (512,10) pre-initialized with dec_b
{
    const int t  = threadIdx.x;
    const int kg = t & 7;           // k-slice (lane bits 0..2): f4 column within row
    const int fg = (t >> 3) & 3;    // filter group (lane bits 3..4): 4 filters each
    const int bg = t >> 5;          // batch group 0..7: 8 batches each
    const int bx = blockIdx.x;
    const int p  = bx >> 3;         // 0..99 (8 consecutive blocks share p -> warm w in L2)
    const int bt = bx & 7;
    const int pr = p / 10, pc = p % 10;
    const int b0 = bt * 64 + bg * 8;

    // kg==7 would read k=28..31 (past the patch row): clamp to 24, mask later.
    const int kq = (kg < 7) ? kg * 4 : 24;

    const float* xb = x + (size_t)b0 * HWIMG + (size_t)(pr * 28) * WROW + pc * 28 + kq;
    const float* wb = weight + (size_t)(fg * 4 * PNUM + p) * 784 + kq;

    float acc[8][4];
#pragma unroll
    for (int i = 0; i < 8; ++i)
#pragma unroll
        for (int j = 0; j < 4; ++j) acc[i][j] = 0.f;

    for (int kr = 0; kr < KSZ; ++kr) {
        const float* xr = xb + kr * WROW;
        const float* wr = wb + kr * KSZ;
        // 12 independent loads — compiler clusters them, one vmcnt wait per row.
        float4 a0 = *reinterpret_cast<const float4*>(xr + 0 * HWIMG);
        float4 a1 = *reinterpret_cast<const float4*>(xr + 1 * HWIMG);
        float4 a2 = *reinterpret_cast<const float4*>(xr + 2 * HWIMG);
        float4 a3 = *reinterpret_cast<const float4*>(xr + 3 * HWIMG);
        float4 a4 = *reinterpret_cast<const float4*>(xr + 4 * HWIMG);
        float4 a5 = *reinterpret_cast<const float4*>(xr + 5 * HWIMG);
        float4 a6 = *reinterpret_cast<const float4*>(xr + 6 * HWIMG);
        float4 a7 = *reinterpret_cast<const float4*>(xr + 7 * HWIMG);
        float4 w0 = *reinterpret_cast<const float4*>(wr + 0 * (PNUM * 784));
        float4 w1 = *reinterpret_cast<const float4*>(wr + 1 * (PNUM * 784));
        float4 w2 = *reinterpret_cast<const float4*>(wr + 2 * (PNUM * 784));
        float4 w3 = *reinterpret_cast<const float4*>(wr + 3 * (PNUM * 784));

        float4 av[8] = {a0, a1, a2, a3, a4, a5, a6, a7};
        float4 wv[4] = {w0, w1, w2, w3};
#pragma unroll
        for (int i = 0; i < 8; ++i) {
#pragma unroll
            for (int j = 0; j < 4; ++j) {
                acc[i][j] = fmaf(av[i].x, wv[j].x, acc[i][j]);
                acc[i][j] = fmaf(av[i].y, wv[j].y, acc[i][j]);
                acc[i][j] = fmaf(av[i].z, wv[j].z, acc[i][j]);
                acc[i][j] = fmaf(av[i].w, wv[j].w, acc[i][j]);
            }
        }
    }

    // kg==7 computed duplicated data: zero it.
    const float km = (kg < 7) ? 1.f : 0.f;
#pragma unroll
    for (int i = 0; i < 8; ++i)
#pragma unroll
        for (int j = 0; j < 4; ++j) acc[i][j] *= km;

    // Reduce over kg (lane bits 0..2) — butterfly; all lanes end with the full dot.
#pragma unroll
    for (int d = 1; d < 8; d <<= 1)
#pragma unroll
        for (int i = 0; i < 8; ++i)
#pragma unroll
            for (int j = 0; j < 4; ++j)
                acc[i][j] += __shfl_xor(acc[i][j], d, 64);

    // bias + relu
    float y[8][4];
#pragma unroll
    for (int j = 0; j < 4; ++j) {
        const float bs = bias[(fg * 4 + j) * PNUM + p];
#pragma unroll
        for (int i = 0; i < 8; ++i) {
            float v = acc[i][j] + bs;
            y[i][j] = v > 0.f ? v : 0.f;
        }
    }

    // Decoder: split the 10 outputs across kg lanes 0..4 (2 outputs each).
    float po[8][2];
    const int  o0  = kg * 2;
    const bool act = (kg < 5);
    if (act) {
        float dwv[4][2];
#pragma unroll
        for (int j = 0; j < 4; ++j)
#pragma unroll
            for (int oo = 0; oo < 2; ++oo)
                dwv[j][oo] = dec_w[(size_t)(o0 + oo) * (PNUM * FNUM) + (fg * 4 + j) * PNUM + p];
#pragma unroll
        for (int i = 0; i < 8; ++i)
#pragma unroll
            for (int oo = 0; oo < 2; ++oo) {
                float s = 0.f;
#pragma unroll
                for (int j = 0; j < 4; ++j) s = fmaf(y[i][j], dwv[j][oo], s);
                po[i][oo] = s;
            }
    } else {
#pragma unroll
        for (int i = 0; i < 8; ++i) { po[i][0] = 0.f; po[i][1] = 0.f; }
    }

    // Reduce over fg (lane bits 3..4); kg bits preserved so zero lanes stay isolated.
#pragma unroll
    for (int d = 8; d < 32; d <<= 1)
#pragma unroll
        for (int i = 0; i < 8; ++i)
#pragma unroll
            for (int oo = 0; oo < 2; ++oo)
                po[i][oo] += __shfl_xor(po[i][oo], d, 64);

    if (act && fg == 0) {
#pragma unroll
        for (int i = 0; i < 8; ++i)
#pragma unroll
            for (int oo = 0; oo < 2; ++oo)
                atomicAdd(&out[(size_t)(b0 + i) * ONUM + o0 + oo], po[i][oo]);
    }
}

extern "C" void kernel_launch(void* const* d_in, const int* in_sizes, int n_in,
                              void* d_out, int out_size, void* d_ws, size_t ws_size,
                              hipStream_t stream) {
    const float* x     = (const float*)d_in[0];
    const float* w     = (const float*)d_in[1];
    const float* bias  = (const float*)d_in[2];
    const float* dec_w = (const float*)d_in[3];
    const float* dec_b = (const float*)d_in[4];
    float* out = (float*)d_out;

    init_out<<<(BATCH * ONUM + 255) / 256, 256, 0, stream>>>(dec_b, out);
    lcn_fused<<<(BATCH / 64) * PNUM, 256, 0, stream>>>(x, w, bias, dec_w, out);
}